// Round 1
// baseline (958.331 us; speedup 1.0000x reference)
//
#include <hip/hip_runtime.h>

#define S_LEN 512
#define BATCH 256
#define HID   512
#define VOC   256

typedef __attribute__((ext_vector_type(8))) short short8;
typedef __attribute__((ext_vector_type(4))) float f32x4;
typedef __attribute__((ext_vector_type(2))) _Float16 h2;

static __device__ __forceinline__ unsigned short f2bf(float f){
  unsigned int u = __builtin_bit_cast(unsigned int, f);
  u += 0x7fffu + ((u >> 16) & 1u);
  return (unsigned short)(u >> 16);
}
static __device__ __forceinline__ unsigned short f2h(float f){
  _Float16 h = (_Float16)f;
  return __builtin_bit_cast(unsigned short, h);
}
static __device__ __forceinline__ float h2f(unsigned short u){
  return (float)__builtin_bit_cast(_Float16, u);
}
static __device__ __forceinline__ float dot2(h2 a, h2 b, float c){
#if __has_builtin(__builtin_amdgcn_fdot2)
  return __builtin_amdgcn_fdot2(a, b, c, false);
#else
  return c + (float)a[0]*(float)b[0] + (float)a[1]*(float)b[1];
#endif
}

// ---------------- prep: expT^T (f16) and W^T (bf16) ----------------
__global__ void prep_kernel(const float* __restrict__ trans, const float* __restrict__ W,
                            unsigned short* __restrict__ expTt, unsigned short* __restrict__ Wt){
  int idx = blockIdx.x * 256 + threadIdx.x;
  if (idx < VOC*VOC){
    int j = idx >> 8, i = idx & 255;                 // expTt[j][i] = exp(T[i][j])
    expTt[idx] = f2h(__expf(trans[i*VOC + j]));
  } else {
    int k2 = idx - VOC*VOC;
    if (k2 < VOC*HID){
      int n = k2 >> 9, k = k2 & 511;                 // Wt[n][k] = bf16(W[k][n])
      Wt[k2] = f2bf(W[k*VOC + n]);
    }
  }
}

// ---------------- GEMM + log_softmax -> f16 logits ----------------
#define LDA 40   // padded row length (ushorts): 80B rows, 16B-aligned, conflict-benign
__global__ __launch_bounds__(256) void gemm_ls_kernel(
    const float* __restrict__ enc, const unsigned short* __restrict__ Wt,
    const float* __restrict__ bias, unsigned short* __restrict__ logits)
{
  __shared__ __align__(16) unsigned short Als[64*LDA];
  __shared__ __align__(16) unsigned short Bls[256*LDA];
  __shared__ float bls[256];

  int tid  = threadIdx.x;
  int lane = tid & 63, wv = tid >> 6;
  int l15  = lane & 15, g4 = lane >> 4;
  int r = tid >> 2, c = (tid & 3) * 8;               // A staging coords
  int rowBlock = blockIdx.x * 64;

  if (tid < 256) bls[tid] = bias[tid];

  f32x4 acc[16];
  #pragma unroll
  for (int j=0;j<16;j++) acc[j] = (f32x4){0.f,0.f,0.f,0.f};

  for (int k0 = 0; k0 < HID; k0 += 32){
    __syncthreads();
    // stage A tile 64x32 (f32 -> bf16)
    const float* ap = enc + (rowBlock + r)*HID + k0 + c;
    float4 a0 = *(const float4*)ap;
    float4 a1 = *(const float4*)(ap + 4);
    short8 av;
    av[0]=(short)f2bf(a0.x); av[1]=(short)f2bf(a0.y); av[2]=(short)f2bf(a0.z); av[3]=(short)f2bf(a0.w);
    av[4]=(short)f2bf(a1.x); av[5]=(short)f2bf(a1.y); av[6]=(short)f2bf(a1.z); av[7]=(short)f2bf(a1.w);
    *(short8*)&Als[r*LDA + c] = av;
    // stage B tile: row n = tid, 32 bf16 from Wt
    const uint4* bp = (const uint4*)(Wt + tid*HID + k0);
    uint4 b0 = bp[0], b1 = bp[1], b2 = bp[2], b3 = bp[3];
    uint4* bd = (uint4*)&Bls[tid*LDA];
    bd[0]=b0; bd[1]=b1; bd[2]=b2; bd[3]=b3;
    __syncthreads();
    // MFMA: wave wv owns rows [wv*16, wv*16+16)
    short8 afr = *(const short8*)&Als[(wv*16 + l15)*LDA + g4*8];
    #pragma unroll
    for (int j=0;j<16;j++){
      short8 bfr = *(const short8*)&Bls[(j*16 + l15)*LDA + g4*8];
      acc[j] = __builtin_amdgcn_mfma_f32_16x16x32_bf16(afr, bfr, acc[j], 0, 0, 0);
    }
  }

  // epilogue: row-wise log_softmax, store f16
  #pragma unroll
  for (int reg=0; reg<4; ++reg){
    float x[16];
    float m = -1e30f;
    #pragma unroll
    for (int j=0;j<16;j++){ x[j] = acc[j][reg] + bls[j*16 + l15]; m = fmaxf(m, x[j]); }
    #pragma unroll
    for (int msk=1; msk<16; msk<<=1) m = fmaxf(m, __shfl_xor(m, msk));
    float s = 0.f;
    #pragma unroll
    for (int j=0;j<16;j++) s += __expf(x[j] - m);
    #pragma unroll
    for (int msk=1; msk<16; msk<<=1) s += __shfl_xor(s, msk);
    float lse = m + __logf(s);
    int row = rowBlock + wv*16 + g4*4 + reg;
    unsigned short* op = logits + row*VOC + l15;
    #pragma unroll
    for (int j=0;j<16;j++) op[j*16] = f2h(x[j] - lse);
  }
}

// ---------------- CRF scan: one block per batch ----------------
__global__ __launch_bounds__(512) void scan_kernel(
    const unsigned short* __restrict__ logits,
    const unsigned short* __restrict__ expTt,
    const float* __restrict__ trans,
    const float* __restrict__ startT,
    const float* __restrict__ endT,
    const int* __restrict__ targets,
    const int* __restrict__ lengths,
    float* __restrict__ out)
{
  int b   = blockIdx.x;
  int tid = threadIdx.x;
  int j   = tid & 255;
  int g   = tid >> 8;            // 0 or 1: i-range half
  int len = lengths[b];

  __shared__ __align__(16) float Zs[256];
  __shared__ __align__(16) float ph[2][256];
  __shared__ __align__(16) unsigned short e16[256];
  __shared__ float wmax[4];
  __shared__ float red[16];

  // expT column j, half g -> 64 half2 registers
  h2 wreg[64];
  {
    const uint4* cp = (const uint4*)(expTt + j*VOC + g*128);
    #pragma unroll
    for (int p=0;p<16;p++){
      uint4 q = cp[p];
      wreg[4*p+0] = __builtin_bit_cast(h2, q.x);
      wreg[4*p+1] = __builtin_bit_cast(h2, q.y);
      wreg[4*p+2] = __builtin_bit_cast(h2, q.z);
      wreg[4*p+3] = __builtin_bit_cast(h2, q.w);
    }
  }

  // init Z0 = start + logits[0]
  if (tid < 256){
    float z = startT[j] + h2f(logits[b*VOC + j]);
    Zs[j] = z;
    float m = z;
    #pragma unroll
    for (int msk=1; msk<64; msk<<=1) m = fmaxf(m, __shfl_xor(m, msk));
    if ((tid & 63) == 0) wmax[tid >> 6] = m;
  }
  __syncthreads();

  float mcur = 0.f, lg = 0.f;
  for (int t = 1; t < len; ++t){
    // phase A (threads 0..255): e = exp(Z - m); prefetch logit row
    if (tid < 256){
      lg   = h2f(logits[(t*BATCH + b)*VOC + j]);     // consumed in phase C
      mcur = fmaxf(fmaxf(wmax[0], wmax[1]), fmaxf(wmax[2], wmax[3]));
      e16[j] = f2h(__expf(Zs[j] - mcur));
    }
    __syncthreads();
    // phase B (all 512): partial dot of e with expT column
    {
      float acc0 = 0.f, acc1 = 0.f;
      const uint4* ep = (const uint4*)(e16 + g*128);
      #pragma unroll
      for (int p=0;p<16;p++){
        uint4 q = ep[p];                             // wave-uniform LDS broadcast
        acc0 = dot2(__builtin_bit_cast(h2, q.x), wreg[4*p+0], acc0);
        acc1 = dot2(__builtin_bit_cast(h2, q.y), wreg[4*p+1], acc1);
        acc0 = dot2(__builtin_bit_cast(h2, q.z), wreg[4*p+2], acc0);
        acc1 = dot2(__builtin_bit_cast(h2, q.w), wreg[4*p+3], acc1);
      }
      ph[g][j] = acc0 + acc1;
    }
    __syncthreads();
    // phase C (threads 0..255): finalize Zn, new running max
    if (tid < 256){
      float zn = mcur + __logf(ph[0][j] + ph[1][j]) + lg;
      Zs[j] = zn;
      float m = zn;
      #pragma unroll
      for (int msk=1; msk<64; msk<<=1) m = fmaxf(m, __shfl_xor(m, msk));
      if ((tid & 63) == 0) wmax[tid >> 6] = m;
    }
    __syncthreads();
  }

  // Zp = logsumexp(Zf + end)
  float v = 0.f;
  if (tid < 256){
    v = Zs[j] + endT[j];
    float m = v;
    #pragma unroll
    for (int msk=1; msk<64; msk<<=1) m = fmaxf(m, __shfl_xor(m, msk));
    if ((tid & 63) == 0) red[tid >> 6] = m;
  }
  __syncthreads();
  float m3 = fmaxf(fmaxf(red[0], red[1]), fmaxf(red[2], red[3]));
  if (tid < 256){
    float e = __expf(v - m3);
    #pragma unroll
    for (int msk=1; msk<64; msk<<=1) e += __shfl_xor(e, msk);
    if ((tid & 63) == 0) red[4 + (tid >> 6)] = e;
  }
  // gold-path score: thread tid handles timestep t = tid
  float sc = 0.f;
  {
    int t = tid;
    if (t < len){
      int tg = targets[t*BATCH + b];
      sc = h2f(logits[(t*BATCH + b)*VOC + tg]);
      if (t >= 1){
        int tp = targets[(t-1)*BATCH + b];
        sc += trans[tp*VOC + tg];
      } else {
        sc += startT[tg];
      }
      if (t == len - 1) sc += endT[tg];
    }
    #pragma unroll
    for (int msk=1; msk<64; msk<<=1) sc += __shfl_xor(sc, msk);
    if ((tid & 63) == 0) red[8 + (tid >> 6)] = sc;
  }
  __syncthreads();
  if (tid == 0){
    float s3 = red[4] + red[5] + red[6] + red[7];
    float Zp = m3 + __logf(s3);
    float score = red[8]+red[9]+red[10]+red[11]+red[12]+red[13]+red[14]+red[15];
    atomicAdd(out, (Zp - score) * (1.0f / BATCH));
  }
}

// ---------------- host ----------------
extern "C" void kernel_launch(void* const* d_in, const int* in_sizes, int n_in,
                              void* d_out, int out_size, void* d_ws, size_t ws_size,
                              hipStream_t stream){
  const float* enc    = (const float*)d_in[0];
  const float* W      = (const float*)d_in[1];
  const float* bias   = (const float*)d_in[2];
  const float* trans  = (const float*)d_in[3];
  const float* startT = (const float*)d_in[4];
  const float* endT   = (const float*)d_in[5];
  const int*   targets= (const int*)d_in[6];
  const int*   lengths= (const int*)d_in[7];

  unsigned short* logits = (unsigned short*)d_ws;                         // S*B*V f16 = 64 MiB
  unsigned short* expTt  = logits + (size_t)S_LEN*BATCH*VOC;              // V*V f16
  unsigned short* Wt     = expTt + (size_t)VOC*VOC;                       // V*H bf16

  hipMemsetAsync(d_out, 0, sizeof(float)*out_size, stream);
  prep_kernel<<<(VOC*VOC + VOC*HID)/256, 256, 0, stream>>>(trans, W, expTt, Wt);
  gemm_ls_kernel<<<(S_LEN*BATCH)/64, 256, 0, stream>>>(enc, Wt, bias, logits);
  scan_kernel<<<BATCH, 512, 0, stream>>>(logits, expTt, trans, startT, endT, targets, lengths, (float*)d_out);
}

// Round 2
// 872.453 us; speedup vs baseline: 1.0984x; 1.0984x over previous
//
#include <hip/hip_runtime.h>

#define S_LEN 512
#define BATCH 256
#define HID   512
#define VOC   256

typedef __attribute__((ext_vector_type(8))) short short8;
typedef __attribute__((ext_vector_type(4))) float f32x4;
typedef __attribute__((ext_vector_type(2))) _Float16 h2;

static __device__ __forceinline__ unsigned short f2bf(float f){
  unsigned int u = __builtin_bit_cast(unsigned int, f);
  u += 0x7fffu + ((u >> 16) & 1u);
  return (unsigned short)(u >> 16);
}
static __device__ __forceinline__ unsigned short f2h(float f){
  _Float16 h = (_Float16)f;
  return __builtin_bit_cast(unsigned short, h);
}
static __device__ __forceinline__ float h2f(unsigned short u){
  return (float)__builtin_bit_cast(_Float16, u);
}
static __device__ __forceinline__ float dot2(h2 a, h2 b, float c){
#if __has_builtin(__builtin_amdgcn_fdot2)
  return __builtin_amdgcn_fdot2(a, b, c, false);
#else
  return c + (float)a[0]*(float)b[0] + (float)a[1]*(float)b[1];
#endif
}
static __device__ __forceinline__ float wave_sum(float v){
  #pragma unroll
  for (int m = 1; m < 64; m <<= 1) v += __shfl_xor(v, m);
  return v;
}
// barrier with LDS-visibility only: does NOT drain vmcnt, so global prefetches
// stay in flight across it.
static __device__ __forceinline__ void sync_lds(){
  asm volatile("s_waitcnt lgkmcnt(0)" ::: "memory");
  __builtin_amdgcn_s_barrier();
  asm volatile("" ::: "memory");
}

// ---------------- prep: expT^T (f16) and W^T (bf16) ----------------
__global__ void prep_kernel(const float* __restrict__ trans, const float* __restrict__ W,
                            unsigned short* __restrict__ expTt, unsigned short* __restrict__ Wt){
  int idx = blockIdx.x * 256 + threadIdx.x;
  if (idx < VOC*VOC){
    int j = idx >> 8, i = idx & 255;                 // expTt[j][i] = exp(T[i][j])
    expTt[idx] = f2h(__expf(trans[i*VOC + j]));
  } else {
    int k2 = idx - VOC*VOC;
    if (k2 < VOC*HID){
      int n = k2 >> 9, k = k2 & 511;                 // Wt[n][k] = bf16(W[k][n])
      Wt[k2] = f2bf(W[k*VOC + n]);
    }
  }
}

// ---------------- GEMM + softmax -> f16 probs ----------------
#define BM  128
#define BK  64
#define LDT 72   // LDS row stride (ushorts): 144B rows, 16B-aligned, 2-way bank alias only

__global__ __launch_bounds__(512, 4) void gemm_ls_kernel(
    const float* __restrict__ enc, const unsigned short* __restrict__ Wt,
    const float* __restrict__ bias, unsigned short* __restrict__ probs)
{
  __shared__ __align__(16) unsigned short Als[BM * LDT];
  __shared__ __align__(16) unsigned short Bls[VOC * LDT];
  __shared__ float pmax[4][BM];
  __shared__ float psum[4][BM];

  const int tid  = threadIdx.x;
  const int lane = tid & 63, w = tid >> 6;
  const int l15  = lane & 15, g4 = lane >> 4;
  const int wm   = w >> 2, wn = w & 3;               // wave grid 2(M) x 4(N)
  const int row0 = blockIdx.x * BM;

  const int ar = tid >> 2, ac = (tid & 3) * 16;      // A staging: row, f32-col
  const int bn = tid >> 1, bk = (tid & 1) * 32;      // B staging: row(n), k-col

  f32x4 acc[4][4];
  #pragma unroll
  for (int i = 0; i < 4; i++)
    #pragma unroll
    for (int j = 0; j < 4; j++) acc[i][j] = (f32x4){0.f,0.f,0.f,0.f};

  const float* aBase = enc + (size_t)(row0 + ar) * HID + ac;
  const unsigned short* bBase = Wt + (size_t)bn * HID + bk;

  for (int k0 = 0; k0 < HID; k0 += BK){
    __syncthreads();
    // stage A: 16 f32 -> 16 bf16 per thread
    const float4* ap = (const float4*)(aBase + k0);
    float4 a0 = ap[0], a1 = ap[1], a2 = ap[2], a3 = ap[3];
    short8 s0, s1;
    s0[0]=(short)f2bf(a0.x); s0[1]=(short)f2bf(a0.y); s0[2]=(short)f2bf(a0.z); s0[3]=(short)f2bf(a0.w);
    s0[4]=(short)f2bf(a1.x); s0[5]=(short)f2bf(a1.y); s0[6]=(short)f2bf(a1.z); s0[7]=(short)f2bf(a1.w);
    s1[0]=(short)f2bf(a2.x); s1[1]=(short)f2bf(a2.y); s1[2]=(short)f2bf(a2.z); s1[3]=(short)f2bf(a2.w);
    s1[4]=(short)f2bf(a3.x); s1[5]=(short)f2bf(a3.y); s1[6]=(short)f2bf(a3.z); s1[7]=(short)f2bf(a3.w);
    *(short8*)&Als[ar*LDT + ac]     = s0;
    *(short8*)&Als[ar*LDT + ac + 8] = s1;
    // stage B: 32 bf16 per thread
    const uint4* bp = (const uint4*)(bBase + k0);
    uint4 q0 = bp[0], q1 = bp[1], q2 = bp[2], q3 = bp[3];
    uint4* bd = (uint4*)&Bls[bn*LDT + bk];
    bd[0]=q0; bd[1]=q1; bd[2]=q2; bd[3]=q3;
    __syncthreads();
    // compute: wave tile 64x64, 32 MFMAs
    #pragma unroll
    for (int s = 0; s < 2; s++){
      short8 af[4];
      #pragma unroll
      for (int mi = 0; mi < 4; mi++)
        af[mi] = *(const short8*)&Als[(wm*64 + mi*16 + l15)*LDT + s*32 + g4*8];
      #pragma unroll
      for (int ni = 0; ni < 4; ni++){
        short8 bf = *(const short8*)&Bls[(wn*64 + ni*16 + l15)*LDT + s*32 + g4*8];
        #pragma unroll
        for (int mi = 0; mi < 4; mi++)
          acc[mi][ni] = __builtin_amdgcn_mfma_f32_16x16x32_bf16(af[mi], bf, acc[mi][ni], 0, 0, 0);
      }
    }
  }

  // ---- fused softmax epilogue (probs, f16) ----
  float bcol[4];
  #pragma unroll
  for (int ni = 0; ni < 4; ni++) bcol[ni] = bias[wn*64 + ni*16 + l15];

  #pragma unroll
  for (int mi = 0; mi < 4; mi++){
    #pragma unroll
    for (int r = 0; r < 4; r++){
      float m = acc[mi][0][r] + bcol[0];
      #pragma unroll
      for (int ni = 1; ni < 4; ni++) m = fmaxf(m, acc[mi][ni][r] + bcol[ni]);
      #pragma unroll
      for (int msk = 1; msk < 16; msk <<= 1) m = fmaxf(m, __shfl_xor(m, msk));
      if (l15 == 0) pmax[wn][wm*64 + mi*16 + g4*4 + r] = m;
    }
  }
  __syncthreads();
  float rowm[4][4];
  #pragma unroll
  for (int mi = 0; mi < 4; mi++)
    #pragma unroll
    for (int r = 0; r < 4; r++){
      int rl = wm*64 + mi*16 + g4*4 + r;
      rowm[mi][r] = fmaxf(fmaxf(pmax[0][rl], pmax[1][rl]), fmaxf(pmax[2][rl], pmax[3][rl]));
    }
  #pragma unroll
  for (int mi = 0; mi < 4; mi++){
    #pragma unroll
    for (int r = 0; r < 4; r++){
      float sum = 0.f;
      #pragma unroll
      for (int ni = 0; ni < 4; ni++){
        float e = __expf(acc[mi][ni][r] + bcol[ni] - rowm[mi][r]);
        acc[mi][ni][r] = e;
        sum += e;
      }
      #pragma unroll
      for (int msk = 1; msk < 16; msk <<= 1) sum += __shfl_xor(sum, msk);
      if (l15 == 0) psum[wn][wm*64 + mi*16 + g4*4 + r] = sum;
    }
  }
  __syncthreads();
  #pragma unroll
  for (int mi = 0; mi < 4; mi++){
    #pragma unroll
    for (int r = 0; r < 4; r++){
      int rl = wm*64 + mi*16 + g4*4 + r;
      float sv = (psum[0][rl] + psum[1][rl]) + (psum[2][rl] + psum[3][rl]);
      float invs = __builtin_amdgcn_rcpf(sv);     // err self-corrects in scan's log s
      size_t base = (size_t)(row0 + rl) * VOC + wn*64 + l15;
      #pragma unroll
      for (int ni = 0; ni < 4; ni++)
        probs[base + ni*16] = f2h(acc[mi][ni][r] * invs);
    }
  }
}

// ---------------- CRF scan in prob space: 1 block/batch, 256 thr, 1 barrier/step ----------------
__global__ __launch_bounds__(256) void scan_kernel(
    const unsigned short* __restrict__ probs,
    const unsigned short* __restrict__ expTt,
    const float* __restrict__ trans,
    const float* __restrict__ startT,
    const float* __restrict__ endT,
    const int* __restrict__ targets,
    const int* __restrict__ lengths,
    float* __restrict__ out)
{
  const int b = blockIdx.x;
  const int j = threadIdx.x;          // thread j owns output state j
  const int len = lengths[b];

  __shared__ __align__(16) unsigned short ubuf[2][VOC];  // unnormalized alpha, f16
  __shared__ __align__(16) float pb[2][4];               // per-wave partial sums
  __shared__ float red[8];

  // expT column j -> 128 h2 registers
  h2 wreg[128];
  {
    const uint4* cp = (const uint4*)(expTt + (size_t)j * VOC);
    #pragma unroll
    for (int p = 0; p < 32; p++){
      uint4 q = cp[p];
      wreg[4*p+0] = __builtin_bit_cast(h2, q.x);
      wreg[4*p+1] = __builtin_bit_cast(h2, q.y);
      wreg[4*p+2] = __builtin_bit_cast(h2, q.z);
      wreg[4*p+3] = __builtin_bit_cast(h2, q.w);
    }
  }

  // init: u0 = exp(start) * p0   (Z = C + log u, C = 0)
  float aval = __expf(startT[j]) * h2f(probs[b*VOC + j]);
  ubuf[0][j] = f2h(aval);
  {
    float ws = wave_sum(aval);
    if ((j & 63) == 0) pb[0][j >> 6] = ws;
  }
  unsigned short pnext = probs[((size_t)BATCH + b) * VOC + j];   // t=1 row prefetch
  float C = 0.f;
  sync_lds();

  for (int t = 1; t < len; ++t){
    const int cur = t & 1, prv = cur ^ 1;
    // prev-step sum (one step late): normalization + C update, errors self-correct
    float4 pp = *(const float4*)&pb[prv][0];
    float s = (pp.x + pp.y) + (pp.z + pp.w);
    float inv = __builtin_amdgcn_rcpf(s);
    C += __logf(s);
    float pcur = h2f(pnext);
    int tn = (t + 1 < S_LEN) ? (t + 1) : (S_LEN - 1);
    pnext = probs[((size_t)tn * BATCH + b) * VOC + j];            // prefetch (survives sync_lds)
    // dot: u_{t-1} . expT[:,j]   (wave-uniform LDS broadcasts, 128 x v_dot2)
    const uint4* up = (const uint4*)&ubuf[prv][0];
    float a0 = 0.f, a1 = 0.f, a2 = 0.f, a3 = 0.f;
    #pragma unroll
    for (int q = 0; q < 32; q++){
      uint4 v = up[q];
      a0 = dot2(__builtin_bit_cast(h2, v.x), wreg[4*q+0], a0);
      a1 = dot2(__builtin_bit_cast(h2, v.y), wreg[4*q+1], a1);
      a2 = dot2(__builtin_bit_cast(h2, v.z), wreg[4*q+2], a2);
      a3 = dot2(__builtin_bit_cast(h2, v.w), wreg[4*q+3], a3);
    }
    float qd = (a0 + a1) + (a2 + a3);
    aval = qd * inv * pcur;                                      // u_t[j], sum in [0.74, 1.35]
    ubuf[cur][j] = f2h(aval);
    float ws = wave_sum(aval);
    if ((j & 63) == 0) pb[cur][j >> 6] = ws;
    sync_lds();                                                  // ONE barrier per step
  }

  // Zp = C + log( sum_j u_j * exp(end_j) )
  {
    float v = aval * __expf(endT[j]);
    float ws = wave_sum(v);
    if ((j & 63) == 0) red[j >> 6] = ws;
  }
  // gold-path score: thread j handles t = j and t = j + 256
  float sc = 0.f;
  #pragma unroll
  for (int half = 0; half < 2; ++half){
    int t = j + half * 256;
    if (t < len){
      int tg = targets[t*BATCH + b];
      float p = h2f(probs[((size_t)t * BATCH + b) * VOC + tg]);
      sc += __logf(fmaxf(p, 1e-12f));
      if (t >= 1) sc += trans[targets[(t-1)*BATCH + b]*VOC + tg];
      else        sc += startT[tg];
      if (t == len - 1) sc += endT[tg];
    }
  }
  {
    float ws = wave_sum(sc);
    if ((j & 63) == 0) red[4 + (j >> 6)] = ws;
  }
  sync_lds();
  if (j == 0){
    float tot = (red[0] + red[1]) + (red[2] + red[3]);
    float Zp = C + __logf(tot);
    float score = (red[4] + red[5]) + (red[6] + red[7]);
    atomicAdd(out, (Zp - score) * (1.0f / BATCH));
  }
}

// ---------------- host ----------------
extern "C" void kernel_launch(void* const* d_in, const int* in_sizes, int n_in,
                              void* d_out, int out_size, void* d_ws, size_t ws_size,
                              hipStream_t stream){
  const float* enc    = (const float*)d_in[0];
  const float* W      = (const float*)d_in[1];
  const float* bias   = (const float*)d_in[2];
  const float* trans  = (const float*)d_in[3];
  const float* startT = (const float*)d_in[4];
  const float* endT   = (const float*)d_in[5];
  const int*   targets= (const int*)d_in[6];
  const int*   lengths= (const int*)d_in[7];

  unsigned short* probs = (unsigned short*)d_ws;                       // S*B*V f16 = 64 MiB
  unsigned short* expTt = probs + (size_t)S_LEN*BATCH*VOC;             // V*V f16
  unsigned short* Wt    = expTt + (size_t)VOC*VOC;                     // V*H bf16

  hipMemsetAsync(d_out, 0, sizeof(float)*out_size, stream);
  prep_kernel<<<(VOC*VOC + VOC*HID)/256, 256, 0, stream>>>(trans, W, expTt, Wt);
  gemm_ls_kernel<<<(S_LEN*BATCH)/BM, 512, 0, stream>>>(enc, Wt, bias, probs);
  scan_kernel<<<BATCH, 256, 0, stream>>>(probs, expTt, trans, startT, endT, targets, lengths, (float*)d_out);
}